// Round 24
// baseline (68.710 us; speedup 1.0000x reference)
//
#include <hip/hip_runtime.h>

// RoIAlign multi-level extractor (FPN), matches jax reference.
//   K=1024 rois, C=256, OUT=7, SR=2, strides {4,8,16,32}, B=2
//
// v17 = v16 (verified 66.6us) + ONE change: 512-thread blocks (8 waves),
//   grid K*8 (32 ch/block, still 4 iters/block).
//   Rationale: conflicts proved off-critical-path (v13/v16: -19% conflicts,
//   0% time). Remaining un-amortized term = per-block prologue (~30 meta
//   gathers + 5 int divides + weight setup ~1-1.5k cy) paid 16x/roi.
//   8 waves/block halves it per channel WITHOUT longer block duration
//   (waves parallel; 4 iters either way) -> v15's L2-locality failure mode
//   does not apply. LDS 8*1280*4=40KB -> 4 blocks/CU -> same 32 waves/CU.
//   Per-wave staging/compute/fences byte-identical to v16.
//   Fallback: v4 kernel (verified 106us) if ws too small.

#define CCH 256
#define NS  14
#define NG  28
#define MSTRIDE 128
#define RECTMAX 1280

__device__ __forceinline__ void gload_lds16(const float* g, float* l) {
  __builtin_amdgcn_global_load_lds(
      (const __attribute__((address_space(1))) void*)g,
      (__attribute__((address_space(3))) void*)l, 16, 0, 0);
}

// ---------------- Kernel A: per-roi metadata ----------------
__global__ __launch_bounds__(256) void roi_meta_kernel(
    const float* __restrict__ rois, int* __restrict__ meta, int K)
{
  const int k = blockIdx.x * 256 + threadIdx.x;
  if (k >= K) return;

  const float r0 = rois[k*5 + 0];
  const float x1 = rois[k*5 + 1], y1 = rois[k*5 + 2];
  const float x2 = rois[k*5 + 3], y2 = rois[k*5 + 4];

  // level: clip(floor(log2(sqrt(w*h)/56 + 1e-6)), 0, 3); f32 op-by-op,
  // log2 via double (matches np.log2 f32 at the binning discontinuities)
  const float scl = __fsqrt_rn(__fmul_rn(__fsub_rn(x2, x1), __fsub_rn(y2, y1)));
  const float tq  = __fadd_rn(__fdiv_rn(scl, 56.0f), 1e-6f);
  const float lg  = (float)log2((double)tq);
  int lvl = (int)floorf(lg);
  lvl = lvl < 0 ? 0 : (lvl > 3 ? 3 : lvl);

  const int   sizeL = 256 >> lvl;
  const float ssc   = 1.0f / (float)(4 << lvl);

  int* m = meta + (size_t)k * MSTRIDE;
  float* mf = (float*)m;
  m[0] = lvl;
  m[1] = (int)r0 * CCH * sizeL * sizeL;

  int lox[NS], hix[NS], loy[NS], hiy[NS];
  float frx[NS], vlx[NS], fry[NS], vly[NS];

  #pragma unroll
  for (int axis = 0; axis < 2; ++axis) {
    const float c1 = axis ? y1 : x1;
    const float c2 = axis ? y2 : x2;
    const float start = __fsub_rn(__fmul_rn(c1, ssc), 0.5f);
    const float rlen  = __fmul_rn(__fsub_rn(c2, c1), ssc);
    const float bwid  = __fdiv_rn(rlen, 7.0f);
    #pragma unroll
    for (int s = 0; s < NS; ++s) {
      const int bin = s >> 1, i = s & 1;
      const float off = ((float)i + 0.5f) * 0.5f;
      const float g = __fadd_rn(__fadd_rn(start, __fmul_rn((float)bin, bwid)),
                                __fmul_rn(off, bwid));
      const float valid = (g >= -1.0f && g <= (float)sizeL) ? 1.0f : 0.0f;
      float cc = fminf(fmaxf(g, 0.0f), (float)(sizeL - 1));
      const int lo0 = (int)floorf(cc);
      int lo, hi; float frac;
      if (lo0 >= sizeL - 1) { lo = sizeL - 1; hi = sizeL - 1; frac = 0.0f; }
      else                  { lo = lo0; hi = lo0 + 1; frac = cc - (float)lo0; }
      if (axis == 0) { lox[s] = lo; hix[s] = hi; frx[s] = frac; vlx[s] = valid; }
      else           { loy[s] = lo; hiy[s] = hi; fry[s] = frac; vly[s] = valid; }
    }
  }

  // g monotone in s -> lo[0] min, hi[13] max
  const int x0r = lox[0];
  const int W_f = hix[NS-1] - x0r + 1;
  int x0a = x0r & ~3;                        // 16B-align rect origin
  const int span = (x0r - x0a) + W_f + 1;    // cols needed incl. pad col
  const int Wp4  = (span + 3) & ~3;          // 4-aligned global span
  if (x0a + Wp4 > sizeL) x0a = sizeL - Wp4;  // keep every row in-plane
  const int y0  = loy[0];
  const int H_f = hiy[NS-1] - y0 + 1;

  // LDS stride: Wl/4 odd -> rows rotate across all 8 bank groups.
  // Fall back to Wl=Wp4 if padded rect would exceed RECTMAX (rare).
  int Wl = ((Wp4 & 7) == 4) ? Wp4 : Wp4 + 4;
  if (H_f * Wl > RECTMAX) Wl = Wp4;

  m[2] = x0a; m[3] = y0; m[4] = H_f * Wl; m[5] = H_f; m[6] = Wp4; m[7] = Wl;

  #pragma unroll
  for (int s = 0; s < NS; ++s) {
    m[8 + s]  = lox[s] - x0a;            // rect-local x (pair read at +1)
    m[22 + s] = (loy[s] - y0) * Wl;      // LDS row offsets (stride Wl)
    m[36 + s] = (hiy[s] - y0) * Wl;
    mf[50 + s] = frx[s]; mf[64 + s] = vlx[s];
    mf[78 + s] = fry[s]; mf[92 + s] = vly[s];
  }
}

// ---------------- Kernel B: flat 16B-staged, barrier-free, 8-wave ----------------
__global__ __launch_bounds__(512) void roi_rect2_kernel(
    const float* __restrict__ f0, const float* __restrict__ f1,
    const float* __restrict__ f2, const float* __restrict__ f3,
    const int* __restrict__ meta, float* __restrict__ out)
{
  const int k     = blockIdx.x >> 3;   // roi
  const int chunk = blockIdx.x & 7;    // 32-channel chunk
  const int t     = threadIdx.x;
  const int w     = t >> 6;            // wave 0..7: stages AND computes chan c0+w
  const int lane  = t & 63;

  __shared__ float s_rect[8][RECTMAX];

  const int* m = meta + (size_t)k * MSTRIDE;
  const float* mf = (const float*)m;
  const int lvl   = m[0];
  const int boff  = m[1];
  const int x0a   = m[2], y0 = m[3];
  const int total = m[4], H_f = m[5], Wp4 = m[6], Wl = m[7];
  const float* fp = (lvl == 0) ? f0 : (lvl == 1) ? f1 : (lvl == 2) ? f2 : f3;
  const int sz = 256 >> lvl;
  const int HW = sz * sz;

  // per-lane flat-staging geometry (channel-invariant): load i covers flat
  // positions [i*256, i*256+256); this lane holds 4 floats at p = i*256+4*lane
  const int nL = (total + 255) >> 8;
  int offv[5];
  #pragma unroll
  for (int i = 0; i < 5; ++i) {
    const int p = (i << 8) + (lane << 2);
    int row = p / Wl;                  // runtime div, once per block
    int col = p - row * Wl;
    if (row >= H_f) row = H_f - 1;     // tail clamp (stays in-plane)
    if (col >= Wp4) col = Wp4 - 4;     // pad granule: harmless in-plane dup
    offv[i] = row * sz + col;
  }

  // compute decode: wave = channel, lane = bin (active < 49)
  const int bin  = lane < 49 ? lane : 48;
  const bool act = lane < 49;
  const int ph   = bin / 7;
  const int pw   = bin - ph * 7;

  int   a_lo[4], a_hi[4];
  float w00[4], w01[4], w10[4], w11[4];
  #pragma unroll
  for (int i = 0; i < 2; ++i) {
    const int sy = 2 * ph + i;
    const int yol = m[22 + sy], yoh = m[36 + sy];
    const float fy = mf[78 + sy], vy = mf[92 + sy];
    #pragma unroll
    for (int j = 0; j < 2; ++j) {
      const int sx = 2 * pw + j;
      const int xl = m[8 + sx];
      const float fx = mf[50 + sx], vx = mf[64 + sx];
      const int s4 = 2 * i + j;
      a_lo[s4] = yol + xl;
      a_hi[s4] = yoh + xl;
      const float msk = vy * vx * 0.25f;
      const float wy0 = 1.0f - fy, wy1 = fy;
      const float wx0 = 1.0f - fx, wx1 = fx;
      w00[s4] = wy0 * wx0 * msk;
      w01[s4] = wy0 * wx1 * msk;
      w10[s4] = wy1 * wx0 * msk;
      w11[s4] = wy1 * wx1 * msk;
    }
  }

  const float* base = fp + boff + (size_t)y0 * sz + x0a;
  float* outp = out + ((size_t)k * CCH + chunk * 32 + w) * 49 + bin;

  for (int it = 0; it < 4; ++it) {
    const int c0 = chunk * 32 + it * 8;

    // ---- stage channel c0+w into s_rect[w]: <=5 x global_load_lds(16B) ----
    {
      const float* src = base + (size_t)(c0 + w) * HW;
      float* dst0 = &s_rect[w][0];
      #pragma unroll
      for (int i = 0; i < 5; ++i) {
        if (i < nL) gload_lds16(src + offv[i], dst0 + (i << 8));
      }
    }
    // wave-private wait: only THIS wave's staging loads must land
    asm volatile("s_waitcnt vmcnt(0)" ::: "memory");

    if (act) {
      const float* rp = &s_rect[w][0];   // own wave's buffer only
      float acc = 0.0f;
      #pragma unroll
      for (int s4 = 0; s4 < 4; ++s4) {
        const float g00 = rp[a_lo[s4]];
        const float g01 = rp[a_lo[s4] + 1];   // pair -> ds_read2_b32
        const float g10 = rp[a_hi[s4]];
        const float g11 = rp[a_hi[s4] + 1];
        acc = __builtin_fmaf(w00[s4], g00, acc);
        acc = __builtin_fmaf(w01[s4], g01, acc);
        acc = __builtin_fmaf(w10[s4], g10, acc);
        acc = __builtin_fmaf(w11[s4], g11, acc);
      }
      *outp = acc;
    }
    outp += 8 * 49;   // 8 channels * 49 bins per iteration

    // ensure this wave's LDS reads are retired before next-iter overwrite
    asm volatile("s_waitcnt lgkmcnt(0)" ::: "memory");
  }
}

// ---------------- v4 fallback (verified 106us) ----------------
__global__ __launch_bounds__(256) void roi_extract_kernel(
    const float* __restrict__ f0, const float* __restrict__ f1,
    const float* __restrict__ f2, const float* __restrict__ f3,
    const float* __restrict__ rois, float* __restrict__ out, int K)
{
  const int k     = blockIdx.x >> 3;
  const int chunk = blockIdx.x & 7;
  const int t     = threadIdx.x;

  __shared__ int   s_xidx[NG];
  __shared__ int   s_yoff[NG];
  __shared__ float s_fx[NS], s_vx[NS], s_fy[NS], s_vy[NS];
  __shared__ int   s_lvl, s_boff;
  __shared__ float s_grid[8][NG][NG + 1];

  if (t < NG) {
    const float r0 = rois[k*5 + 0];
    const float x1 = rois[k*5 + 1], y1 = rois[k*5 + 2];
    const float x2 = rois[k*5 + 3], y2 = rois[k*5 + 4];
    const float scl = __fsqrt_rn(__fmul_rn(__fsub_rn(x2, x1), __fsub_rn(y2, y1)));
    const float tq  = __fadd_rn(__fdiv_rn(scl, 56.0f), 1e-6f);
    const float lg  = (float)log2((double)tq);
    int lvl = (int)floorf(lg);
    lvl = lvl < 0 ? 0 : (lvl > 3 ? 3 : lvl);
    const int   sizeL = 256 >> lvl;
    const float ssc   = 1.0f / (float)(4 << lvl);
    const int axis = t / NS;
    const int s    = t - axis*NS;
    const float c1 = axis ? y1 : x1;
    const float c2 = axis ? y2 : x2;
    const float start = __fsub_rn(__fmul_rn(c1, ssc), 0.5f);
    const float rlen  = __fmul_rn(__fsub_rn(c2, c1), ssc);
    const float bwid  = __fdiv_rn(rlen, 7.0f);
    const int bin = s >> 1, i = s & 1;
    const float off = ((float)i + 0.5f) * 0.5f;
    const float g = __fadd_rn(__fadd_rn(start, __fmul_rn((float)bin, bwid)),
                              __fmul_rn(off, bwid));
    const float valid = (g >= -1.0f && g <= (float)sizeL) ? 1.0f : 0.0f;
    float cc = fminf(fmaxf(g, 0.0f), (float)(sizeL - 1));
    const int lo0 = (int)floorf(cc);
    int lo, hi; float frac;
    if (lo0 >= sizeL - 1) { lo = sizeL - 1; hi = sizeL - 1; frac = 0.0f; }
    else                  { lo = lo0; hi = lo0 + 1; frac = cc - (float)lo0; }
    if (axis == 0) { s_xidx[s] = lo; s_xidx[NS + s] = hi; s_fx[s] = frac; s_vx[s] = valid; }
    else           { s_yoff[s] = lo * sizeL; s_yoff[NS + s] = hi * sizeL;
                     s_fy[s] = frac; s_vy[s] = valid; }
    if (t == 0) { s_lvl = lvl; s_boff = (int)r0 * CCH * sizeL * sizeL; }
  }
  __syncthreads();

  const int lvl = s_lvl;
  const float* fp = (lvl == 0) ? f0 : (lvl == 1) ? f1 : (lvl == 2) ? f2 : f3;
  const int sz = 256 >> lvl;
  const int HW = sz * sz;
  const float* bp = fp + s_boff;
  const int csub = t >> 5;
  const int lane = t & 31;
  const int xo   = (lane < NG) ? s_xidx[lane] : 0;

  for (int cg = 0; cg < 4; ++cg) {
    const int c0 = chunk * 32 + cg * 8;
    const float* cp = bp + (size_t)(c0 + csub) * HW;
    if (lane < NG) {
      #pragma unroll
      for (int r = 0; r < NG; ++r) s_grid[csub][r][lane] = cp[s_yoff[r] + xo];
    }
    __syncthreads();
    for (int o = t; o < 8 * 49; o += 256) {
      const int cs  = o / 49;
      const int bin = o - cs * 49;
      const int ph  = bin / 7, pw = bin - ph * 7;
      float acc = 0.0f;
      #pragma unroll
      for (int i = 0; i < 2; ++i) {
        const int sy = 2 * ph + i;
        const float fy = s_fy[sy], vy = s_vy[sy];
        #pragma unroll
        for (int j = 0; j < 2; ++j) {
          const int sx = 2 * pw + j;
          const float fx = s_fx[sx], vx = s_vx[sx];
          const float g00 = s_grid[cs][sy][sx];
          const float g01 = s_grid[cs][sy][NS + sx];
          const float g10 = s_grid[cs][NS + sy][sx];
          const float g11 = s_grid[cs][NS + sy][NS + sx];
          const float sval = (1.0f - fy) * ((1.0f - fx) * g00 + fx * g01)
                           + fy * ((1.0f - fx) * g10 + fx * g11);
          acc += sval * (vy * vx);
        }
      }
      out[((size_t)k * CCH + c0 + cs) * 49 + bin] = acc * 0.25f;
    }
    __syncthreads();
  }
}

extern "C" void kernel_launch(void* const* d_in, const int* in_sizes, int n_in,
                              void* d_out, int out_size, void* d_ws, size_t ws_size,
                              hipStream_t stream) {
  const float* f0   = (const float*)d_in[0];
  const float* f1   = (const float*)d_in[1];
  const float* f2   = (const float*)d_in[2];
  const float* f3   = (const float*)d_in[3];
  const float* rois = (const float*)d_in[4];
  float* out = (float*)d_out;
  const int K = in_sizes[4] / 5;

  const size_t need = (size_t)K * MSTRIDE * sizeof(int);
  if (ws_size >= need) {
    int* meta = (int*)d_ws;
    hipLaunchKernelGGL(roi_meta_kernel, dim3((K + 255) / 256), dim3(256), 0, stream,
                       rois, meta, K);
    hipLaunchKernelGGL(roi_rect2_kernel, dim3(K * 8), dim3(512), 0, stream,
                       f0, f1, f2, f3, meta, out);
  } else {
    hipLaunchKernelGGL(roi_extract_kernel, dim3(K * 8), dim3(256), 0, stream,
                       f0, f1, f2, f3, rois, out, K);
  }
}

// Round 25
// 66.372 us; speedup vs baseline: 1.0352x; 1.0352x over previous
//
#include <hip/hip_runtime.h>

// RoIAlign multi-level extractor (FPN), matches jax reference.
//   K=1024 rois, C=256, OUT=7, SR=2, strides {4,8,16,32}, B=2
//
// v18 = v16 (best verified: 66.6us; v14-equivalent 66.4us) — RESTORED.
//   v17 (8-wave blocks) regressed to 68.7 (occupancy 68->62). Lever sweep
//   complete: conflicts off-critical-path (v12/v13/v16), barriers removed
//   (v14 +1.6%), dbuf - (v7), coarser blocks - (v15/v17), finer 0 (v9),
//   table precompute 0 (v10). Structure plateau: 66.4-66.6us, no pipe
//   saturated (VALU 37%, HBM 19%, LDS ~50%, occ 68%) -> issue/latency
//   bound jointly. 2.1x over baseline (140us).
//   Structure: meta kernel (exact-fp per-roi sampling geometry, double-log2
//   level binning) -> per-roi rect staged flat via 16B global_load_lds,
//   granule-odd LDS stride, wave-autonomous barrier-free loop (wave w
//   stages AND reads only s_rect[w]; own-wave vmcnt/lgkmcnt fences),
//   K*16 grid, LDS 20480B -> 8 blocks/CU.
//   Fallback: v4 kernel (verified 106us) if ws too small.

#define CCH 256
#define NS  14
#define NG  28
#define MSTRIDE 128
#define RECTMAX 1280

__device__ __forceinline__ void gload_lds16(const float* g, float* l) {
  __builtin_amdgcn_global_load_lds(
      (const __attribute__((address_space(1))) void*)g,
      (__attribute__((address_space(3))) void*)l, 16, 0, 0);
}

// ---------------- Kernel A: per-roi metadata ----------------
__global__ __launch_bounds__(256) void roi_meta_kernel(
    const float* __restrict__ rois, int* __restrict__ meta, int K)
{
  const int k = blockIdx.x * 256 + threadIdx.x;
  if (k >= K) return;

  const float r0 = rois[k*5 + 0];
  const float x1 = rois[k*5 + 1], y1 = rois[k*5 + 2];
  const float x2 = rois[k*5 + 3], y2 = rois[k*5 + 4];

  // level: clip(floor(log2(sqrt(w*h)/56 + 1e-6)), 0, 3); f32 op-by-op,
  // log2 via double (matches np.log2 f32 at the binning discontinuities)
  const float scl = __fsqrt_rn(__fmul_rn(__fsub_rn(x2, x1), __fsub_rn(y2, y1)));
  const float tq  = __fadd_rn(__fdiv_rn(scl, 56.0f), 1e-6f);
  const float lg  = (float)log2((double)tq);
  int lvl = (int)floorf(lg);
  lvl = lvl < 0 ? 0 : (lvl > 3 ? 3 : lvl);

  const int   sizeL = 256 >> lvl;
  const float ssc   = 1.0f / (float)(4 << lvl);

  int* m = meta + (size_t)k * MSTRIDE;
  float* mf = (float*)m;
  m[0] = lvl;
  m[1] = (int)r0 * CCH * sizeL * sizeL;

  int lox[NS], hix[NS], loy[NS], hiy[NS];
  float frx[NS], vlx[NS], fry[NS], vly[NS];

  #pragma unroll
  for (int axis = 0; axis < 2; ++axis) {
    const float c1 = axis ? y1 : x1;
    const float c2 = axis ? y2 : x2;
    const float start = __fsub_rn(__fmul_rn(c1, ssc), 0.5f);
    const float rlen  = __fmul_rn(__fsub_rn(c2, c1), ssc);
    const float bwid  = __fdiv_rn(rlen, 7.0f);
    #pragma unroll
    for (int s = 0; s < NS; ++s) {
      const int bin = s >> 1, i = s & 1;
      const float off = ((float)i + 0.5f) * 0.5f;
      const float g = __fadd_rn(__fadd_rn(start, __fmul_rn((float)bin, bwid)),
                                __fmul_rn(off, bwid));
      const float valid = (g >= -1.0f && g <= (float)sizeL) ? 1.0f : 0.0f;
      float cc = fminf(fmaxf(g, 0.0f), (float)(sizeL - 1));
      const int lo0 = (int)floorf(cc);
      int lo, hi; float frac;
      if (lo0 >= sizeL - 1) { lo = sizeL - 1; hi = sizeL - 1; frac = 0.0f; }
      else                  { lo = lo0; hi = lo0 + 1; frac = cc - (float)lo0; }
      if (axis == 0) { lox[s] = lo; hix[s] = hi; frx[s] = frac; vlx[s] = valid; }
      else           { loy[s] = lo; hiy[s] = hi; fry[s] = frac; vly[s] = valid; }
    }
  }

  // g monotone in s -> lo[0] min, hi[13] max
  const int x0r = lox[0];
  const int W_f = hix[NS-1] - x0r + 1;
  int x0a = x0r & ~3;                        // 16B-align rect origin
  const int span = (x0r - x0a) + W_f + 1;    // cols needed incl. pad col
  const int Wp4  = (span + 3) & ~3;          // 4-aligned global span
  if (x0a + Wp4 > sizeL) x0a = sizeL - Wp4;  // keep every row in-plane
  const int y0  = loy[0];
  const int H_f = hiy[NS-1] - y0 + 1;

  // LDS stride: Wl/4 odd -> rows rotate across all 8 bank groups.
  // Fall back to Wl=Wp4 if padded rect would exceed RECTMAX (rare).
  int Wl = ((Wp4 & 7) == 4) ? Wp4 : Wp4 + 4;
  if (H_f * Wl > RECTMAX) Wl = Wp4;

  m[2] = x0a; m[3] = y0; m[4] = H_f * Wl; m[5] = H_f; m[6] = Wp4; m[7] = Wl;

  #pragma unroll
  for (int s = 0; s < NS; ++s) {
    m[8 + s]  = lox[s] - x0a;            // rect-local x (pair read at +1)
    m[22 + s] = (loy[s] - y0) * Wl;      // LDS row offsets (stride Wl)
    m[36 + s] = (hiy[s] - y0) * Wl;
    mf[50 + s] = frx[s]; mf[64 + s] = vlx[s];
    mf[78 + s] = fry[s]; mf[92 + s] = vly[s];
  }
}

// ---------------- Kernel B: flat 16B-staged, barrier-free ----------------
__global__ __launch_bounds__(256) void roi_rect2_kernel(
    const float* __restrict__ f0, const float* __restrict__ f1,
    const float* __restrict__ f2, const float* __restrict__ f3,
    const int* __restrict__ meta, float* __restrict__ out)
{
  const int k     = blockIdx.x >> 4;   // roi
  const int chunk = blockIdx.x & 15;   // 16-channel chunk
  const int t     = threadIdx.x;
  const int w     = t >> 6;            // wave 0..3: stages AND computes chan c0+w
  const int lane  = t & 63;

  __shared__ float s_rect[4][RECTMAX];

  const int* m = meta + (size_t)k * MSTRIDE;
  const float* mf = (const float*)m;
  const int lvl   = m[0];
  const int boff  = m[1];
  const int x0a   = m[2], y0 = m[3];
  const int total = m[4], H_f = m[5], Wp4 = m[6], Wl = m[7];
  const float* fp = (lvl == 0) ? f0 : (lvl == 1) ? f1 : (lvl == 2) ? f2 : f3;
  const int sz = 256 >> lvl;
  const int HW = sz * sz;

  // per-lane flat-staging geometry (channel-invariant): load i covers flat
  // positions [i*256, i*256+256); this lane holds 4 floats at p = i*256+4*lane
  const int nL = (total + 255) >> 8;
  int offv[5];
  #pragma unroll
  for (int i = 0; i < 5; ++i) {
    const int p = (i << 8) + (lane << 2);
    int row = p / Wl;                  // runtime div, once per block
    int col = p - row * Wl;
    if (row >= H_f) row = H_f - 1;     // tail clamp (stays in-plane)
    if (col >= Wp4) col = Wp4 - 4;     // pad granule: harmless in-plane dup
    offv[i] = row * sz + col;
  }

  // compute decode: wave = channel, lane = bin (active < 49)
  const int bin  = lane < 49 ? lane : 48;
  const bool act = lane < 49;
  const int ph   = bin / 7;
  const int pw   = bin - ph * 7;

  int   a_lo[4], a_hi[4];
  float w00[4], w01[4], w10[4], w11[4];
  #pragma unroll
  for (int i = 0; i < 2; ++i) {
    const int sy = 2 * ph + i;
    const int yol = m[22 + sy], yoh = m[36 + sy];
    const float fy = mf[78 + sy], vy = mf[92 + sy];
    #pragma unroll
    for (int j = 0; j < 2; ++j) {
      const int sx = 2 * pw + j;
      const int xl = m[8 + sx];
      const float fx = mf[50 + sx], vx = mf[64 + sx];
      const int s4 = 2 * i + j;
      a_lo[s4] = yol + xl;
      a_hi[s4] = yoh + xl;
      const float msk = vy * vx * 0.25f;
      const float wy0 = 1.0f - fy, wy1 = fy;
      const float wx0 = 1.0f - fx, wx1 = fx;
      w00[s4] = wy0 * wx0 * msk;
      w01[s4] = wy0 * wx1 * msk;
      w10[s4] = wy1 * wx0 * msk;
      w11[s4] = wy1 * wx1 * msk;
    }
  }

  const float* base = fp + boff + (size_t)y0 * sz + x0a;
  float* outp = out + ((size_t)k * CCH + chunk * 16 + w) * 49 + bin;

  for (int it = 0; it < 4; ++it) {
    const int c0 = chunk * 16 + it * 4;

    // ---- stage channel c0+w into s_rect[w]: <=5 x global_load_lds(16B) ----
    {
      const float* src = base + (size_t)(c0 + w) * HW;
      float* dst0 = &s_rect[w][0];
      #pragma unroll
      for (int i = 0; i < 5; ++i) {
        if (i < nL) gload_lds16(src + offv[i], dst0 + (i << 8));
      }
    }
    // wave-private wait: only THIS wave's staging loads must land
    asm volatile("s_waitcnt vmcnt(0)" ::: "memory");

    if (act) {
      const float* rp = &s_rect[w][0];   // own wave's buffer only
      float acc = 0.0f;
      #pragma unroll
      for (int s4 = 0; s4 < 4; ++s4) {
        const float g00 = rp[a_lo[s4]];
        const float g01 = rp[a_lo[s4] + 1];   // pair -> ds_read2_b32
        const float g10 = rp[a_hi[s4]];
        const float g11 = rp[a_hi[s4] + 1];
        acc = __builtin_fmaf(w00[s4], g00, acc);
        acc = __builtin_fmaf(w01[s4], g01, acc);
        acc = __builtin_fmaf(w10[s4], g10, acc);
        acc = __builtin_fmaf(w11[s4], g11, acc);
      }
      *outp = acc;
    }
    outp += 196;   // 4 channels * 49 bins

    // ensure this wave's LDS reads are retired before next-iter overwrite
    asm volatile("s_waitcnt lgkmcnt(0)" ::: "memory");
  }
}

// ---------------- v4 fallback (verified 106us) ----------------
__global__ __launch_bounds__(256) void roi_extract_kernel(
    const float* __restrict__ f0, const float* __restrict__ f1,
    const float* __restrict__ f2, const float* __restrict__ f3,
    const float* __restrict__ rois, float* __restrict__ out, int K)
{
  const int k     = blockIdx.x >> 3;
  const int chunk = blockIdx.x & 7;
  const int t     = threadIdx.x;

  __shared__ int   s_xidx[NG];
  __shared__ int   s_yoff[NG];
  __shared__ float s_fx[NS], s_vx[NS], s_fy[NS], s_vy[NS];
  __shared__ int   s_lvl, s_boff;
  __shared__ float s_grid[8][NG][NG + 1];

  if (t < NG) {
    const float r0 = rois[k*5 + 0];
    const float x1 = rois[k*5 + 1], y1 = rois[k*5 + 2];
    const float x2 = rois[k*5 + 3], y2 = rois[k*5 + 4];
    const float scl = __fsqrt_rn(__fmul_rn(__fsub_rn(x2, x1), __fsub_rn(y2, y1)));
    const float tq  = __fadd_rn(__fdiv_rn(scl, 56.0f), 1e-6f);
    const float lg  = (float)log2((double)tq);
    int lvl = (int)floorf(lg);
    lvl = lvl < 0 ? 0 : (lvl > 3 ? 3 : lvl);
    const int   sizeL = 256 >> lvl;
    const float ssc   = 1.0f / (float)(4 << lvl);
    const int axis = t / NS;
    const int s    = t - axis*NS;
    const float c1 = axis ? y1 : x1;
    const float c2 = axis ? y2 : x2;
    const float start = __fsub_rn(__fmul_rn(c1, ssc), 0.5f);
    const float rlen  = __fmul_rn(__fsub_rn(c2, c1), ssc);
    const float bwid  = __fdiv_rn(rlen, 7.0f);
    const int bin = s >> 1, i = s & 1;
    const float off = ((float)i + 0.5f) * 0.5f;
    const float g = __fadd_rn(__fadd_rn(start, __fmul_rn((float)bin, bwid)),
                              __fmul_rn(off, bwid));
    const float valid = (g >= -1.0f && g <= (float)sizeL) ? 1.0f : 0.0f;
    float cc = fminf(fmaxf(g, 0.0f), (float)(sizeL - 1));
    const int lo0 = (int)floorf(cc);
    int lo, hi; float frac;
    if (lo0 >= sizeL - 1) { lo = sizeL - 1; hi = sizeL - 1; frac = 0.0f; }
    else                  { lo = lo0; hi = lo0 + 1; frac = cc - (float)lo0; }
    if (axis == 0) { s_xidx[s] = lo; s_xidx[NS + s] = hi; s_fx[s] = frac; s_vx[s] = valid; }
    else           { s_yoff[s] = lo * sizeL; s_yoff[NS + s] = hi * sizeL;
                     s_fy[s] = frac; s_vy[s] = valid; }
    if (t == 0) { s_lvl = lvl; s_boff = (int)r0 * CCH * sizeL * sizeL; }
  }
  __syncthreads();

  const int lvl = s_lvl;
  const float* fp = (lvl == 0) ? f0 : (lvl == 1) ? f1 : (lvl == 2) ? f2 : f3;
  const int sz = 256 >> lvl;
  const int HW = sz * sz;
  const float* bp = fp + s_boff;
  const int csub = t >> 5;
  const int lane = t & 31;
  const int xo   = (lane < NG) ? s_xidx[lane] : 0;

  for (int cg = 0; cg < 4; ++cg) {
    const int c0 = chunk * 32 + cg * 8;
    const float* cp = bp + (size_t)(c0 + csub) * HW;
    if (lane < NG) {
      #pragma unroll
      for (int r = 0; r < NG; ++r) s_grid[csub][r][lane] = cp[s_yoff[r] + xo];
    }
    __syncthreads();
    for (int o = t; o < 8 * 49; o += 256) {
      const int cs  = o / 49;
      const int bin = o - cs * 49;
      const int ph  = bin / 7, pw = bin - ph * 7;
      float acc = 0.0f;
      #pragma unroll
      for (int i = 0; i < 2; ++i) {
        const int sy = 2 * ph + i;
        const float fy = s_fy[sy], vy = s_vy[sy];
        #pragma unroll
        for (int j = 0; j < 2; ++j) {
          const int sx = 2 * pw + j;
          const float fx = s_fx[sx], vx = s_vx[sx];
          const float g00 = s_grid[cs][sy][sx];
          const float g01 = s_grid[cs][sy][NS + sx];
          const float g10 = s_grid[cs][NS + sy][sx];
          const float g11 = s_grid[cs][NS + sy][NS + sx];
          const float sval = (1.0f - fy) * ((1.0f - fx) * g00 + fx * g01)
                           + fy * ((1.0f - fx) * g10 + fx * g11);
          acc += sval * (vy * vx);
        }
      }
      out[((size_t)k * CCH + c0 + cs) * 49 + bin] = acc * 0.25f;
    }
    __syncthreads();
  }
}

extern "C" void kernel_launch(void* const* d_in, const int* in_sizes, int n_in,
                              void* d_out, int out_size, void* d_ws, size_t ws_size,
                              hipStream_t stream) {
  const float* f0   = (const float*)d_in[0];
  const float* f1   = (const float*)d_in[1];
  const float* f2   = (const float*)d_in[2];
  const float* f3   = (const float*)d_in[3];
  const float* rois = (const float*)d_in[4];
  float* out = (float*)d_out;
  const int K = in_sizes[4] / 5;

  const size_t need = (size_t)K * MSTRIDE * sizeof(int);
  if (ws_size >= need) {
    int* meta = (int*)d_ws;
    hipLaunchKernelGGL(roi_meta_kernel, dim3((K + 255) / 256), dim3(256), 0, stream,
                       rois, meta, K);
    hipLaunchKernelGGL(roi_rect2_kernel, dim3(K * 16), dim3(256), 0, stream,
                       f0, f1, f2, f3, meta, out);
  } else {
    hipLaunchKernelGGL(roi_extract_kernel, dim3(K * 8), dim3(256), 0, stream,
                       f0, f1, f2, f3, rois, out, K);
  }
}